// Round 13
// baseline (1123.850 us; speedup 1.0000x reference)
//
#include <hip/hip_runtime.h>

#define N_NODES 50000
#define N_EDGES 640000
#define TOT_E (N_EDGES + N_NODES)
#define NB 196              // dst buckets: dst>>8 (= ceil(N/256))
#define BCAP 4608           // bucket capacity (mean 3520, ~18 sigma headroom)
#define EPW 4096            // edges per workgroup in scatter
#define NG 128
#define NCLS 10
#define NEG 0.2f

typedef unsigned int u32;
typedef unsigned short u16;
typedef unsigned char u8;
typedef __attribute__((ext_vector_type(8))) short s16x8;
typedef __attribute__((ext_vector_type(4))) float f32x4;
typedef __attribute__((ext_vector_type(2))) float f32x2;

__device__ inline u32 bf16rne(float f) {
  u32 u = __float_as_uint(f);
  return (u + 0x7FFFu + ((u >> 16) & 1u)) >> 16;
}

// decode 16 fp8 (one uint4 = 128-bit slice of a row) into 16 named accumulators
#define ACC16(e, h)                                                  \
  do {                                                               \
    f32x2 p0 = __builtin_amdgcn_cvt_pk_f32_fp8((int)(h).x, false);   \
    f32x2 p1 = __builtin_amdgcn_cvt_pk_f32_fp8((int)(h).x, true);    \
    f32x2 p2 = __builtin_amdgcn_cvt_pk_f32_fp8((int)(h).y, false);   \
    f32x2 p3 = __builtin_amdgcn_cvt_pk_f32_fp8((int)(h).y, true);    \
    f32x2 p4 = __builtin_amdgcn_cvt_pk_f32_fp8((int)(h).z, false);   \
    f32x2 p5 = __builtin_amdgcn_cvt_pk_f32_fp8((int)(h).z, true);    \
    f32x2 p6 = __builtin_amdgcn_cvt_pk_f32_fp8((int)(h).w, false);   \
    f32x2 p7 = __builtin_amdgcn_cvt_pk_f32_fp8((int)(h).w, true);    \
    a0  = fmaf((e), p0[0], a0);  a1  = fmaf((e), p0[1], a1);         \
    a2  = fmaf((e), p1[0], a2);  a3  = fmaf((e), p1[1], a3);         \
    a4  = fmaf((e), p2[0], a4);  a5  = fmaf((e), p2[1], a5);         \
    a6  = fmaf((e), p3[0], a6);  a7  = fmaf((e), p3[1], a7);         \
    a8  = fmaf((e), p4[0], a8);  a9  = fmaf((e), p4[1], a9);         \
    a10 = fmaf((e), p5[0], a10); a11 = fmaf((e), p5[1], a11);        \
    a12 = fmaf((e), p6[0], a12); a13 = fmaf((e), p6[1], a13);        \
    a14 = fmaf((e), p7[0], a14); a15 = fmaf((e), p7[1], a15);        \
  } while (0)

// ---------------- prep: zero bcur/psum + bf16-transposed Wt + fp32-transposed Wf3t ----------------
__global__ __launch_bounds__(256) void prep_kernel(int* __restrict__ bcur,
                                                   float* __restrict__ psum,
                                                   const float* __restrict__ W0,
                                                   const float* __restrict__ W1,
                                                   const float* __restrict__ W2,
                                                   u16* __restrict__ Wt,
                                                   const float* __restrict__ Wf3,
                                                   float* __restrict__ Wf3t) {
  int i = blockIdx.x * 256 + threadIdx.x;   // 65536 threads
  if (i < NB) bcur[i] = 0;
  if (i < NG * 128) psum[i] = 0.f;
  if (i < 3 * 128 * 128) {
    int l = i >> 14, c = (i >> 7) & 127, k = i & 127;
    const float* W = (l == 0) ? W0 : ((l == 1) ? W1 : W2);
    Wt[i] = (u16)bf16rne(W[k * 128 + c]);   // Wt[l][c][k] = W_l[k][c]
  } else if (i < 3 * 128 * 128 + NCLS * 512) {
    int j = i - 3 * 128 * 128;
    int c = j >> 9, k = j & 511;
    Wf3t[j] = Wf3[k * NCLS + c];            // Wf3t[c][k]
  }
}

// ---------------- bucketed scatter (XCD-local writes) ----------------
__global__ __launch_bounds__(256) void scatter_kernel(const int* __restrict__ ei,
                                                      int* __restrict__ bcur,
                                                      u32* __restrict__ ebuf) {
  __shared__ int hist[NB], basee[NB], lcur[NB];
  int t = threadIdx.x;
  for (int b = t; b < NB; b += 256) hist[b] = 0;
  __syncthreads();
  int e0 = blockIdx.x * EPW;
  int e1 = min(TOT_E, e0 + EPW);
  for (int e = e0 + t; e < e1; e += 256) {
    int d = (e < N_EDGES) ? ei[N_EDGES + e] : (e - N_EDGES);
    atomicAdd(&hist[d >> 8], 1);
  }
  __syncthreads();
  for (int b = t; b < NB; b += 256) {
    int c = hist[b];
    basee[b] = (c > 0) ? atomicAdd(&bcur[b], c) : 0;
    lcur[b] = 0;
  }
  __syncthreads();
  for (int e = e0 + t; e < e1; e += 256) {
    int d, s;
    if (e < N_EDGES) { d = ei[N_EDGES + e]; s = ei[e]; }
    else { d = e - N_EDGES; s = d; }
    int b = d >> 8;
    int r = basee[b] + atomicAdd(&lcur[b], 1);
    if (r < BCAP) ebuf[(size_t)b * BCAP + r] = ((u32)d << 16) | (u32)s;
  }
}

// ---------------- fused degree-count + local scan + fill (one wg per bucket) ----------------
__global__ __launch_bounds__(256) void degfill_kernel(const int* __restrict__ bcur,
                                                      const u32* __restrict__ ebuf,
                                                      u32* __restrict__ rldeg,
                                                      u16* __restrict__ col) {
  __shared__ int cnt[256], s[256], cur[256];
  int b = blockIdx.x, t = threadIdx.x;
  cnt[t] = 0; __syncthreads();
  int n = min(bcur[b], BCAP);
  const u32* eb = ebuf + (size_t)b * BCAP;
  for (int i = t; i < n; i += 256) atomicAdd(&cnt[(eb[i] >> 16) & 255], 1);
  __syncthreads();
  int v = cnt[t];
  s[t] = v; __syncthreads();
  for (int off = 1; off < 256; off <<= 1) {
    int tmp = (t >= off) ? s[t - off] : 0;
    __syncthreads();
    s[t] += tmp;
    __syncthreads();
  }
  int rl = s[t] - v;
  int node = (b << 8) + t;
  if (node < N_NODES) rldeg[node] = ((u32)rl << 16) | (u32)v;
  cur[t] = rl;
  __syncthreads();
  u16* cb = col + (size_t)b * BCAP;
  for (int i = t; i < n; i += 256) {
    u32 p = eb[i];
    int pos = atomicAdd(&cur[(p >> 16) & 255], 1);
    cb[pos] = (u16)(p & 0xFFFFu);
  }
}

// ---------------- MFMA GEMM + fused alpha + fp8 pack ----------------
template <bool CVT>
__global__ __launch_bounds__(64) void gemm_mfma(const void* __restrict__ Xin,
                                                const u16* __restrict__ Wt,
                                                const float* __restrict__ avs,
                                                const float* __restrict__ avd,
                                                u8* __restrict__ Hf8,
                                                float* __restrict__ as_out,
                                                float* __restrict__ ad_out) {
  __shared__ __align__(16) u8 st8[16 * 128];
  int lane = threadIdx.x;
  int m0 = blockIdx.x * 16;
  int ar = lane & 15, kg = lane >> 4;
  f32x4 acc[8];
#pragma unroll
  for (int n = 0; n < 8; n++) acc[n] = (f32x4){0.f, 0.f, 0.f, 0.f};
#pragma unroll
  for (int ks = 0; ks < 4; ks++) {
    s16x8 a;
    if (CVT) {
      const float* xr = (const float*)Xin + (size_t)(m0 + ar) * 128 + ks * 32 + kg * 8;
      float4 f0 = *(const float4*)xr;
      float4 f1 = *(const float4*)(xr + 4);
      a[0] = (short)bf16rne(f0.x); a[1] = (short)bf16rne(f0.y);
      a[2] = (short)bf16rne(f0.z); a[3] = (short)bf16rne(f0.w);
      a[4] = (short)bf16rne(f1.x); a[5] = (short)bf16rne(f1.y);
      a[6] = (short)bf16rne(f1.z); a[7] = (short)bf16rne(f1.w);
    } else {
      a = *(const s16x8*)((const u16*)Xin + (size_t)(m0 + ar) * 128 + ks * 32 + kg * 8);
    }
#pragma unroll
    for (int n = 0; n < 8; n++) {
      s16x8 b = *(const s16x8*)(Wt + (size_t)(n * 16 + ar) * 128 + ks * 32 + kg * 8);
      acc[n] = __builtin_amdgcn_mfma_f32_16x16x32_bf16(a, b, acc[n], 0, 0, 0);
    }
  }
  // fused alpha on fp32 accumulators (exact)
  float avsv[8], advv[8];
#pragma unroll
  for (int n = 0; n < 8; n++) { avsv[n] = avs[n * 16 + ar]; advv[n] = avd[n * 16 + ar]; }
#pragma unroll
  for (int reg = 0; reg < 4; reg++) {
    float ps = 0.f, pd = 0.f;
#pragma unroll
    for (int n = 0; n < 8; n++) {
      ps = fmaf(acc[n][reg], avsv[n], ps);
      pd = fmaf(acc[n][reg], advv[n], pd);
    }
#pragma unroll
    for (int off = 1; off < 16; off <<= 1) {
      ps += __shfl_xor(ps, off, 64);
      pd += __shfl_xor(pd, off, 64);
    }
    if (ar == 0) {
      int row = m0 + kg * 4 + reg;
      as_out[row] = ps; ad_out[row] = pd;
    }
  }
  // fp8 store via LDS repack
#pragma unroll
  for (int n = 0; n < 8; n++)
#pragma unroll
    for (int reg = 0; reg < 4; reg++) {
      float v = acc[n][reg];
      u32 p = (u32)__builtin_amdgcn_cvt_pk_fp8_f32(v, v, 0, false);
      st8[(kg * 4 + reg) * 128 + n * 16 + ar] = (u8)(p & 0xFFu);
    }
  __syncthreads();
#pragma unroll
  for (int i = 0; i < 2; i++) {
    int idx = i * 64 + lane;              // uint4 index into 2KB tile
    int r = idx >> 3;
    int c16 = (idx & 7) * 16;
    *(uint4*)(Hf8 + (size_t)(m0 + r) * 128 + c16) = *(const uint4*)&st8[r * 128 + c16];
  }
}

// ---------------- fused segment-softmax + aggregation + bias + relu ----------------
// fp8 gather: 8-lane groups x uint4 (one 128B row per group-step), 16 named accumulators.
// psum==null: write bf16 row to Ob. psum!=null (layer 3): atomicAdd into psum[batch[node]].
__global__ __launch_bounds__(256) void agg_kernel(
    const u8* __restrict__ Hf8, const float* __restrict__ asv,
    const float* __restrict__ adv, const u32* __restrict__ rldeg,
    const u16* __restrict__ col, const float* __restrict__ bias,
    u16* __restrict__ Ob, float* __restrict__ psum, const int* __restrict__ batch) {
  int gid = blockIdx.x * blockDim.x + threadIdx.x;
  int node = gid >> 6;
  if (node >= N_NODES) return;
  int lane = threadIdx.x & 63;
  int q = lane >> 3;          // 8 edge-groups
  int li = lane & 7;          // owns dims li*16 .. li*16+15
  u32 rd = rldeg[node];
  int r0 = (node >> 8) * BCAP + (int)(rd >> 16);
  int r1 = r0 + (int)(rd & 0xFFFFu);
  float ad = adv[node];
  float a0 = 0.f, a1 = 0.f, a2 = 0.f, a3 = 0.f, a4 = 0.f, a5 = 0.f, a6 = 0.f, a7 = 0.f;
  float a8 = 0.f, a9 = 0.f, a10 = 0.f, a11 = 0.f, a12 = 0.f, a13 = 0.f, a14 = 0.f, a15 = 0.f;
  float den = 0.f;

  for (int base = r0; base < r1; base += 64) {
    int cnt = min(64, r1 - base);
    int s_l = 0; float ex_l = 0.f;
    if (lane < cnt) {
      s_l = (int)col[base + lane];
      float tt = asv[s_l] + ad;
      tt = (tt > 0.f) ? tt : NEG * tt;
      ex_l = __expf(tt);
    }
    float d = ex_l;
#pragma unroll
    for (int off = 32; off; off >>= 1) d += __shfl_xor(d, off, 64);
    den += d;

    int j = 0;
    for (; j + 16 <= cnt; j += 16) {
      int i0 = j + q, i1 = j + 8 + q;
      int s0 = __shfl(s_l, i0, 64); float e0 = __shfl(ex_l, i0, 64);
      int s1 = __shfl(s_l, i1, 64); float e1 = __shfl(ex_l, i1, 64);
      uint4 h0 = *(const uint4*)(Hf8 + (size_t)s0 * 128 + li * 16);
      uint4 h1 = *(const uint4*)(Hf8 + (size_t)s1 * 128 + li * 16);
      ACC16(e0, h0);
      ACC16(e1, h1);
    }
    for (; j < cnt; j += 8) {
      int i0 = j + q;
      int s0 = __shfl(s_l, i0, 64); float e0 = __shfl(ex_l, i0, 64);
      if (i0 < cnt) {
        uint4 h0 = *(const uint4*)(Hf8 + (size_t)s0 * 128 + li * 16);
        ACC16(e0, h0);
      }
    }
  }
  // merge the 8 group partial sums (disjoint edges, same dims)
  a0  += __shfl_xor(a0, 8, 64);  a0  += __shfl_xor(a0, 16, 64);  a0  += __shfl_xor(a0, 32, 64);
  a1  += __shfl_xor(a1, 8, 64);  a1  += __shfl_xor(a1, 16, 64);  a1  += __shfl_xor(a1, 32, 64);
  a2  += __shfl_xor(a2, 8, 64);  a2  += __shfl_xor(a2, 16, 64);  a2  += __shfl_xor(a2, 32, 64);
  a3  += __shfl_xor(a3, 8, 64);  a3  += __shfl_xor(a3, 16, 64);  a3  += __shfl_xor(a3, 32, 64);
  a4  += __shfl_xor(a4, 8, 64);  a4  += __shfl_xor(a4, 16, 64);  a4  += __shfl_xor(a4, 32, 64);
  a5  += __shfl_xor(a5, 8, 64);  a5  += __shfl_xor(a5, 16, 64);  a5  += __shfl_xor(a5, 32, 64);
  a6  += __shfl_xor(a6, 8, 64);  a6  += __shfl_xor(a6, 16, 64);  a6  += __shfl_xor(a6, 32, 64);
  a7  += __shfl_xor(a7, 8, 64);  a7  += __shfl_xor(a7, 16, 64);  a7  += __shfl_xor(a7, 32, 64);
  a8  += __shfl_xor(a8, 8, 64);  a8  += __shfl_xor(a8, 16, 64);  a8  += __shfl_xor(a8, 32, 64);
  a9  += __shfl_xor(a9, 8, 64);  a9  += __shfl_xor(a9, 16, 64);  a9  += __shfl_xor(a9, 32, 64);
  a10 += __shfl_xor(a10, 8, 64); a10 += __shfl_xor(a10, 16, 64); a10 += __shfl_xor(a10, 32, 64);
  a11 += __shfl_xor(a11, 8, 64); a11 += __shfl_xor(a11, 16, 64); a11 += __shfl_xor(a11, 32, 64);
  a12 += __shfl_xor(a12, 8, 64); a12 += __shfl_xor(a12, 16, 64); a12 += __shfl_xor(a12, 32, 64);
  a13 += __shfl_xor(a13, 8, 64); a13 += __shfl_xor(a13, 16, 64); a13 += __shfl_xor(a13, 32, 64);
  a14 += __shfl_xor(a14, 8, 64); a14 += __shfl_xor(a14, 16, 64); a14 += __shfl_xor(a14, 32, 64);
  a15 += __shfl_xor(a15, 8, 64); a15 += __shfl_xor(a15, 16, 64); a15 += __shfl_xor(a15, 32, 64);

  if (q == 0) {
    float inv = 1.f / (den + 1e-16f);
    const float* bb = bias + li * 16;
    float4 b0 = *(const float4*)(bb);
    float4 b1 = *(const float4*)(bb + 4);
    float4 b2 = *(const float4*)(bb + 8);
    float4 b3 = *(const float4*)(bb + 12);
    float o0  = fmaxf(fmaf(a0,  inv, b0.x), 0.f);
    float o1  = fmaxf(fmaf(a1,  inv, b0.y), 0.f);
    float o2  = fmaxf(fmaf(a2,  inv, b0.z), 0.f);
    float o3  = fmaxf(fmaf(a3,  inv, b0.w), 0.f);
    float o4  = fmaxf(fmaf(a4,  inv, b1.x), 0.f);
    float o5  = fmaxf(fmaf(a5,  inv, b1.y), 0.f);
    float o6  = fmaxf(fmaf(a6,  inv, b1.z), 0.f);
    float o7  = fmaxf(fmaf(a7,  inv, b1.w), 0.f);
    float o8  = fmaxf(fmaf(a8,  inv, b2.x), 0.f);
    float o9  = fmaxf(fmaf(a9,  inv, b2.y), 0.f);
    float o10 = fmaxf(fmaf(a10, inv, b2.z), 0.f);
    float o11 = fmaxf(fmaf(a11, inv, b2.w), 0.f);
    float o12 = fmaxf(fmaf(a12, inv, b3.x), 0.f);
    float o13 = fmaxf(fmaf(a13, inv, b3.y), 0.f);
    float o14 = fmaxf(fmaf(a14, inv, b3.z), 0.f);
    float o15 = fmaxf(fmaf(a15, inv, b3.w), 0.f);
    if (psum) {                      // layer 3: pool directly
      int g = batch[node];
      float* p = psum + (size_t)g * 128 + li * 16;
      atomicAdd(p + 0, o0);   atomicAdd(p + 1, o1);
      atomicAdd(p + 2, o2);   atomicAdd(p + 3, o3);
      atomicAdd(p + 4, o4);   atomicAdd(p + 5, o5);
      atomicAdd(p + 6, o6);   atomicAdd(p + 7, o7);
      atomicAdd(p + 8, o8);   atomicAdd(p + 9, o9);
      atomicAdd(p + 10, o10); atomicAdd(p + 11, o11);
      atomicAdd(p + 12, o12); atomicAdd(p + 13, o13);
      atomicAdd(p + 14, o14); atomicAdd(p + 15, o15);
    } else {
      uint4 pa, pb;
      pa.x = bf16rne(o0)  | (bf16rne(o1)  << 16);
      pa.y = bf16rne(o2)  | (bf16rne(o3)  << 16);
      pa.z = bf16rne(o4)  | (bf16rne(o5)  << 16);
      pa.w = bf16rne(o6)  | (bf16rne(o7)  << 16);
      pb.x = bf16rne(o8)  | (bf16rne(o9)  << 16);
      pb.y = bf16rne(o10) | (bf16rne(o11) << 16);
      pb.z = bf16rne(o12) | (bf16rne(o13) << 16);
      pb.w = bf16rne(o14) | (bf16rne(o15) << 16);
      u16* ob = Ob + (size_t)node * 128 + li * 16;
      *(uint4*)(ob) = pa;
      *(uint4*)(ob + 8) = pb;
    }
  }
}

// ---------------- FFN head: wide-parallel, short chains ----------------
__device__ inline int lbound(const int* b, int n, int v) {
  int lo = 0, hi = n;
  while (lo < hi) { int m = (lo + hi) >> 1; if (b[m] < v) lo = m + 1; else hi = m; }
  return lo;
}

// ffn1: 512 blocks = (graph, 128-col chunk); 128 threads; counts via binary search
__global__ __launch_bounds__(128) void ffn1_kernel(const float* __restrict__ psum,
                                                   const int* __restrict__ batch,
                                                   const float* __restrict__ Wf1,
                                                   const float* __restrict__ bf1,
                                                   float* __restrict__ z1) {
  __shared__ float prow[128];
  int b = blockIdx.x;
  int g = b >> 2, ch = b & 3;
  int t = threadIdx.x;
  int lo = lbound(batch, N_NODES, g), hi = lbound(batch, N_NODES, g + 1);
  float cnt = fmaxf((float)(hi - lo), 1.f);
  prow[t] = psum[g * 128 + t] / cnt;
  __syncthreads();
  int c = ch * 128 + t;
  float a = bf1[c];
#pragma unroll 8
  for (int k = 0; k < 128; ++k) a = fmaf(prow[k], Wf1[k * 512 + c], a);
  z1[g * 512 + c] = fmaxf(a, 0.f);
}

__global__ __launch_bounds__(256) void ffn2_kernel(const float* __restrict__ z1,
                                                   const float* __restrict__ Wf2,
                                                   const float* __restrict__ bf2,
                                                   float* __restrict__ z2) {
  __shared__ float z1s[512];
  __shared__ float part[256];
  int b = blockIdx.x;
  int g = b >> 3, ch = b & 7;
  int t = threadIdx.x;
  z1s[t] = z1[g * 512 + t];
  z1s[t + 256] = z1[g * 512 + t + 256];
  __syncthreads();
  int c = ch * 64 + (t & 63);
  int kq = t >> 6;
  float a = 0.f;
#pragma unroll 8
  for (int kk = 0; kk < 128; ++kk) {
    int k = kq * 128 + kk;
    a = fmaf(z1s[k], Wf2[k * 512 + c], a);
  }
  part[t] = a;
  __syncthreads();
  if (kq == 0) {
    float s = part[t] + part[t + 64] + part[t + 128] + part[t + 192] + bf2[c];
    z2[g * 512 + c] = fmaxf(s, 0.f);
  }
}

__global__ __launch_bounds__(256) void ffn3_kernel(const float* __restrict__ z2,
                                                   const float* __restrict__ Wf3t,
                                                   const float* __restrict__ bf3,
                                                   float* __restrict__ out) {
  int wid = blockIdx.x * 4 + (threadIdx.x >> 6);  // 0..1279
  int lane = threadIdx.x & 63;
  int g = wid / NCLS, c = wid - g * NCLS;
  float a = 0.f;
#pragma unroll
  for (int j = 0; j < 8; ++j) {
    int k = j * 64 + lane;
    a = fmaf(z2[g * 512 + k], Wf3t[c * 512 + k], a);
  }
#pragma unroll
  for (int off = 32; off; off >>= 1) a += __shfl_xor(a, off, 64);
  if (lane == 0) out[g * NCLS + c] = a + bf3[c];
}

extern "C" void kernel_launch(void* const* d_in, const int* in_sizes, int n_in,
                              void* d_out, int out_size, void* d_ws, size_t ws_size,
                              hipStream_t stream) {
  const float* x   = (const float*)d_in[0];
  const int*   ei  = (const int*)d_in[1];
  const int*   bat = (const int*)d_in[2];
  const float* W[3]  = {(const float*)d_in[3], (const float*)d_in[7],  (const float*)d_in[11]};
  const float* As[3] = {(const float*)d_in[4], (const float*)d_in[8],  (const float*)d_in[12]};
  const float* Ad[3] = {(const float*)d_in[5], (const float*)d_in[9],  (const float*)d_in[13]};
  const float* B[3]  = {(const float*)d_in[6], (const float*)d_in[10], (const float*)d_in[14]};
  const float* Wf1 = (const float*)d_in[15]; const float* bf1 = (const float*)d_in[16];
  const float* Wf2 = (const float*)d_in[17]; const float* bf2 = (const float*)d_in[18];
  const float* Wf3 = (const float*)d_in[19]; const float* bf3 = (const float*)d_in[20];
  float* out = (float*)d_out;

  size_t off = 0;
  auto carve = [&](size_t bytes) {
    void* p = (char*)d_ws + off;
    off += (bytes + 255) & ~(size_t)255;
    return p;
  };
  u16*   Ab0    = (u16*)carve((size_t)N_NODES * 128 * 2);
  u16*   Ab1    = (u16*)carve((size_t)N_NODES * 128 * 2);
  u8*    Hf8    = (u8*)carve((size_t)N_NODES * 128);
  u16*   Wt     = (u16*)carve((size_t)3 * 128 * 128 * 2);
  float* as_    = (float*)carve((size_t)N_NODES * 4);
  float* ad_    = (float*)carve((size_t)N_NODES * 4);
  u32*   rldeg  = (u32*)carve((size_t)N_NODES * 4);
  u16*   col    = (u16*)carve((size_t)NB * BCAP * 2);
  u32*   ebuf   = (u32*)carve((size_t)NB * BCAP * 4);
  int*   bcur   = (int*)carve(NB * 4);
  float* psum   = (float*)carve(NG * 128 * 4);
  float* z1     = (float*)carve(NG * 512 * 4);
  float* z2     = (float*)carve(NG * 512 * 4);
  float* Wf3t   = (float*)carve((size_t)NCLS * 512 * 4);

  // prep (zero bcur/psum, bf16-transpose Wt, fp32-transpose Wf3t)
  prep_kernel<<<256, 256, 0, stream>>>(bcur, psum, W[0], W[1], W[2], Wt, Wf3, Wf3t);

  // bucketed CSR build
  int sgrid = (TOT_E + EPW - 1) / EPW;
  scatter_kernel<<<sgrid, 256, 0, stream>>>(ei, bcur, ebuf);
  degfill_kernel<<<NB, 256, 0, stream>>>(bcur, ebuf, rldeg, col);

  // 3 GAT layers (fp8 gather; layer 3 pools directly into psum)
  int node_waves_grid = (N_NODES * 64 + 255) / 256;
  gemm_mfma<true><<<3125, 64, 0, stream>>>(x, Wt, As[0], Ad[0], Hf8, as_, ad_);
  agg_kernel<<<node_waves_grid, 256, 0, stream>>>(Hf8, as_, ad_, rldeg, col, B[0],
                                                  Ab0, nullptr, nullptr);
  gemm_mfma<false><<<3125, 64, 0, stream>>>(Ab0, Wt + 16384, As[1], Ad[1], Hf8, as_, ad_);
  agg_kernel<<<node_waves_grid, 256, 0, stream>>>(Hf8, as_, ad_, rldeg, col, B[1],
                                                  Ab1, nullptr, nullptr);
  gemm_mfma<false><<<3125, 64, 0, stream>>>(Ab1, Wt + 32768, As[2], Ad[2], Hf8, as_, ad_);
  agg_kernel<<<node_waves_grid, 256, 0, stream>>>(Hf8, as_, ad_, rldeg, col, B[2],
                                                  nullptr, psum, bat);

  // FFN head (wide-parallel; counts via binary search in ffn1)
  ffn1_kernel<<<NG * 4, 128, 0, stream>>>(psum, bat, Wf1, bf1, z1);
  ffn2_kernel<<<NG * 8, 256, 0, stream>>>(z1, Wf2, bf2, z2);
  ffn3_kernel<<<320, 256, 0, stream>>>(z2, Wf3t, bf3, out);
}

// Round 14
// 212.748 us; speedup vs baseline: 5.2826x; 5.2826x over previous
//
#include <hip/hip_runtime.h>

#define N_NODES 50000
#define N_EDGES 640000
#define TOT_E (N_EDGES + N_NODES)
#define NB 196              // dst buckets: dst>>8 (= ceil(N/256))
#define BCAP 4608           // bucket capacity (mean 3520, ~18 sigma headroom)
#define EPW 4096            // edges per workgroup in scatter
#define NG 128
#define NCLS 10
#define NEG 0.2f
#define PCHUNK 50

typedef unsigned int u32;
typedef unsigned short u16;
typedef unsigned char u8;
typedef __attribute__((ext_vector_type(8))) short s16x8;
typedef __attribute__((ext_vector_type(4))) float f32x4;
typedef __attribute__((ext_vector_type(2))) float f32x2;

__device__ inline u32 bf16rne(float f) {
  u32 u = __float_as_uint(f);
  return (u + 0x7FFFu + ((u >> 16) & 1u)) >> 16;
}
__device__ inline float bf2f(u16 v) { return __uint_as_float((u32)v << 16); }

// decode-accumulate: 8 fp8 in (hx,hy) -> named scalar accumulators (no address taken)
#define ACC_FP8X8(e, hx, hy)                                         \
  do {                                                               \
    f32x2 q0 = __builtin_amdgcn_cvt_pk_f32_fp8((int)(hx), false);    \
    f32x2 q1 = __builtin_amdgcn_cvt_pk_f32_fp8((int)(hx), true);     \
    f32x2 q2 = __builtin_amdgcn_cvt_pk_f32_fp8((int)(hy), false);    \
    f32x2 q3 = __builtin_amdgcn_cvt_pk_f32_fp8((int)(hy), true);     \
    acc0 = fmaf((e), q0[0], acc0); acc1 = fmaf((e), q0[1], acc1);    \
    acc2 = fmaf((e), q1[0], acc2); acc3 = fmaf((e), q1[1], acc3);    \
    acc4 = fmaf((e), q2[0], acc4); acc5 = fmaf((e), q2[1], acc5);    \
    acc6 = fmaf((e), q3[0], acc6); acc7 = fmaf((e), q3[1], acc7);    \
  } while (0)

// ---------------- prep: zero bcur/psum/pcnt + bf16-transposed Wt + fp32-transposed Wf3t ----------------
__global__ __launch_bounds__(256) void prep_kernel(int* __restrict__ bcur,
                                                   float* __restrict__ psum,
                                                   float* __restrict__ pcnt,
                                                   const float* __restrict__ W0,
                                                   const float* __restrict__ W1,
                                                   const float* __restrict__ W2,
                                                   u16* __restrict__ Wt,
                                                   const float* __restrict__ Wf3,
                                                   float* __restrict__ Wf3t) {
  int i = blockIdx.x * 256 + threadIdx.x;   // 65536 threads
  if (i < NB) bcur[i] = 0;
  if (i < NG * 128) psum[i] = 0.f;
  if (i < NG) pcnt[i] = 0.f;
  if (i < 3 * 128 * 128) {
    int l = i >> 14, c = (i >> 7) & 127, k = i & 127;
    const float* W = (l == 0) ? W0 : ((l == 1) ? W1 : W2);
    Wt[i] = (u16)bf16rne(W[k * 128 + c]);   // Wt[l][c][k] = W_l[k][c]
  } else if (i < 3 * 128 * 128 + NCLS * 512) {
    int j = i - 3 * 128 * 128;
    int c = j >> 9, k = j & 511;
    Wf3t[j] = Wf3[k * NCLS + c];            // Wf3t[c][k]
  }
}

// ---------------- bucketed scatter (XCD-local writes) ----------------
__global__ __launch_bounds__(256) void scatter_kernel(const int* __restrict__ ei,
                                                      int* __restrict__ bcur,
                                                      u32* __restrict__ ebuf) {
  __shared__ int hist[NB], basee[NB], lcur[NB];
  int t = threadIdx.x;
  for (int b = t; b < NB; b += 256) hist[b] = 0;
  __syncthreads();
  int e0 = blockIdx.x * EPW;
  int e1 = min(TOT_E, e0 + EPW);
  for (int e = e0 + t; e < e1; e += 256) {
    int d = (e < N_EDGES) ? ei[N_EDGES + e] : (e - N_EDGES);
    atomicAdd(&hist[d >> 8], 1);
  }
  __syncthreads();
  for (int b = t; b < NB; b += 256) {
    int c = hist[b];
    basee[b] = (c > 0) ? atomicAdd(&bcur[b], c) : 0;
    lcur[b] = 0;
  }
  __syncthreads();
  for (int e = e0 + t; e < e1; e += 256) {
    int d, s;
    if (e < N_EDGES) { d = ei[N_EDGES + e]; s = ei[e]; }
    else { d = e - N_EDGES; s = d; }
    int b = d >> 8;
    int r = basee[b] + atomicAdd(&lcur[b], 1);
    if (r < BCAP) ebuf[(size_t)b * BCAP + r] = ((u32)d << 16) | (u32)s;
  }
}

// ---------------- fused degree-count + local scan + fill (one wg per bucket) ----------------
__global__ __launch_bounds__(256) void degfill_kernel(const int* __restrict__ bcur,
                                                      const u32* __restrict__ ebuf,
                                                      u32* __restrict__ rldeg,
                                                      u16* __restrict__ col) {
  __shared__ int cnt[256], s[256], cur[256];
  int b = blockIdx.x, t = threadIdx.x;
  cnt[t] = 0; __syncthreads();
  int n = min(bcur[b], BCAP);
  const u32* eb = ebuf + (size_t)b * BCAP;
  for (int i = t; i < n; i += 256) atomicAdd(&cnt[(eb[i] >> 16) & 255], 1);
  __syncthreads();
  int v = cnt[t];
  s[t] = v; __syncthreads();
  for (int off = 1; off < 256; off <<= 1) {
    int tmp = (t >= off) ? s[t - off] : 0;
    __syncthreads();
    s[t] += tmp;
    __syncthreads();
  }
  int rl = s[t] - v;
  int node = (b << 8) + t;
  if (node < N_NODES) rldeg[node] = ((u32)rl << 16) | (u32)v;
  cur[t] = rl;
  __syncthreads();
  u16* cb = col + (size_t)b * BCAP;
  for (int i = t; i < n; i += 256) {
    u32 p = eb[i];
    int pos = atomicAdd(&cur[(p >> 16) & 255], 1);
    cb[pos] = (u16)(p & 0xFFFFu);
  }
}

// ---------------- MFMA GEMM + fused alpha + fp8 pack ----------------
template <bool CVT>
__global__ __launch_bounds__(64) void gemm_mfma(const void* __restrict__ Xin,
                                                const u16* __restrict__ Wt,
                                                const float* __restrict__ avs,
                                                const float* __restrict__ avd,
                                                u8* __restrict__ Hf8,
                                                float* __restrict__ as_out,
                                                float* __restrict__ ad_out) {
  __shared__ __align__(16) u8 st8[16 * 128];
  int lane = threadIdx.x;
  int m0 = blockIdx.x * 16;
  int ar = lane & 15, kg = lane >> 4;
  f32x4 acc[8];
#pragma unroll
  for (int n = 0; n < 8; n++) acc[n] = (f32x4){0.f, 0.f, 0.f, 0.f};
#pragma unroll
  for (int ks = 0; ks < 4; ks++) {
    s16x8 a;
    if (CVT) {
      const float* xr = (const float*)Xin + (size_t)(m0 + ar) * 128 + ks * 32 + kg * 8;
      float4 f0 = *(const float4*)xr;
      float4 f1 = *(const float4*)(xr + 4);
      a[0] = (short)bf16rne(f0.x); a[1] = (short)bf16rne(f0.y);
      a[2] = (short)bf16rne(f0.z); a[3] = (short)bf16rne(f0.w);
      a[4] = (short)bf16rne(f1.x); a[5] = (short)bf16rne(f1.y);
      a[6] = (short)bf16rne(f1.z); a[7] = (short)bf16rne(f1.w);
    } else {
      a = *(const s16x8*)((const u16*)Xin + (size_t)(m0 + ar) * 128 + ks * 32 + kg * 8);
    }
#pragma unroll
    for (int n = 0; n < 8; n++) {
      s16x8 b = *(const s16x8*)(Wt + (size_t)(n * 16 + ar) * 128 + ks * 32 + kg * 8);
      acc[n] = __builtin_amdgcn_mfma_f32_16x16x32_bf16(a, b, acc[n], 0, 0, 0);
    }
  }
  // fused alpha on fp32 accumulators (exact)
  float avsv[8], advv[8];
#pragma unroll
  for (int n = 0; n < 8; n++) { avsv[n] = avs[n * 16 + ar]; advv[n] = avd[n * 16 + ar]; }
#pragma unroll
  for (int reg = 0; reg < 4; reg++) {
    float ps = 0.f, pd = 0.f;
#pragma unroll
    for (int n = 0; n < 8; n++) {
      ps = fmaf(acc[n][reg], avsv[n], ps);
      pd = fmaf(acc[n][reg], advv[n], pd);
    }
#pragma unroll
    for (int off = 1; off < 16; off <<= 1) {
      ps += __shfl_xor(ps, off, 64);
      pd += __shfl_xor(pd, off, 64);
    }
    if (ar == 0) {
      int row = m0 + kg * 4 + reg;
      as_out[row] = ps; ad_out[row] = pd;
    }
  }
  // fp8 store via LDS repack
#pragma unroll
  for (int n = 0; n < 8; n++)
#pragma unroll
    for (int reg = 0; reg < 4; reg++) {
      float v = acc[n][reg];
      u32 p = (u32)__builtin_amdgcn_cvt_pk_fp8_f32(v, v, 0, false);
      st8[(kg * 4 + reg) * 128 + n * 16 + ar] = (u8)(p & 0xFFu);
    }
  __syncthreads();
#pragma unroll
  for (int i = 0; i < 2; i++) {
    int idx = i * 64 + lane;              // uint4 index into 2KB tile
    int r = idx >> 3;
    int c16 = (idx & 7) * 16;
    *(uint4*)(Hf8 + (size_t)(m0 + r) * 128 + c16) = *(const uint4*)&st8[r * 128 + c16];
  }
}

// ---------------- fused segment-softmax + aggregation + bias + relu (bf16 out) ----------------
// fp8 gather (uint2/lane), named-scalar accumulators (no local array address).
__global__ __launch_bounds__(256) void agg_kernel(
    const u8* __restrict__ Hf8, const float* __restrict__ asv,
    const float* __restrict__ adv, const u32* __restrict__ rldeg,
    const u16* __restrict__ col, const float* __restrict__ bias,
    u16* __restrict__ Ob) {
  int gid = blockIdx.x * blockDim.x + threadIdx.x;
  int node = gid >> 6;
  if (node >= N_NODES) return;
  int lane = threadIdx.x & 63;
  int q = lane >> 4;
  int li = lane & 15;
  u32 rd = rldeg[node];
  int r0 = (node >> 8) * BCAP + (int)(rd >> 16);
  int r1 = r0 + (int)(rd & 0xFFFFu);
  float ad = adv[node];
  float acc0 = 0.f, acc1 = 0.f, acc2 = 0.f, acc3 = 0.f;
  float acc4 = 0.f, acc5 = 0.f, acc6 = 0.f, acc7 = 0.f;
  float den = 0.f;

  for (int base = r0; base < r1; base += 64) {
    int cnt = min(64, r1 - base);
    int s_l = 0; float ex_l = 0.f;
    if (lane < cnt) {
      s_l = (int)col[base + lane];
      float tt = asv[s_l] + ad;
      tt = (tt > 0.f) ? tt : NEG * tt;
      ex_l = __expf(tt);
    }
    float d = ex_l;
#pragma unroll
    for (int off = 32; off; off >>= 1) d += __shfl_xor(d, off, 64);
    den += d;

    int j = 0;
    for (; j + 8 <= cnt; j += 8) {
      int i0 = j + q, i1 = j + 4 + q;
      int s0 = __shfl(s_l, i0, 64); float e0 = __shfl(ex_l, i0, 64);
      int s1 = __shfl(s_l, i1, 64); float e1 = __shfl(ex_l, i1, 64);
      uint2 h0 = *(const uint2*)(Hf8 + (size_t)s0 * 128 + li * 8);
      uint2 h1 = *(const uint2*)(Hf8 + (size_t)s1 * 128 + li * 8);
      ACC_FP8X8(e0, h0.x, h0.y);
      ACC_FP8X8(e1, h1.x, h1.y);
    }
    for (; j < cnt; j += 4) {
      int i0 = j + q;
      int s0 = __shfl(s_l, i0, 64); float e0 = __shfl(ex_l, i0, 64);
      if (i0 < cnt) {
        uint2 h0 = *(const uint2*)(Hf8 + (size_t)s0 * 128 + li * 8);
        ACC_FP8X8(e0, h0.x, h0.y);
      }
    }
  }
  acc0 += __shfl_xor(acc0, 16, 64); acc0 += __shfl_xor(acc0, 32, 64);
  acc1 += __shfl_xor(acc1, 16, 64); acc1 += __shfl_xor(acc1, 32, 64);
  acc2 += __shfl_xor(acc2, 16, 64); acc2 += __shfl_xor(acc2, 32, 64);
  acc3 += __shfl_xor(acc3, 16, 64); acc3 += __shfl_xor(acc3, 32, 64);
  acc4 += __shfl_xor(acc4, 16, 64); acc4 += __shfl_xor(acc4, 32, 64);
  acc5 += __shfl_xor(acc5, 16, 64); acc5 += __shfl_xor(acc5, 32, 64);
  acc6 += __shfl_xor(acc6, 16, 64); acc6 += __shfl_xor(acc6, 32, 64);
  acc7 += __shfl_xor(acc7, 16, 64); acc7 += __shfl_xor(acc7, 32, 64);

  if (q == 0) {
    float inv = 1.f / (den + 1e-16f);
    float4 b0 = *(const float4*)(bias + li * 8);
    float4 b1 = *(const float4*)(bias + li * 8 + 4);
    float o0 = fmaxf(fmaf(acc0, inv, b0.x), 0.f);
    float o1 = fmaxf(fmaf(acc1, inv, b0.y), 0.f);
    float o2 = fmaxf(fmaf(acc2, inv, b0.z), 0.f);
    float o3 = fmaxf(fmaf(acc3, inv, b0.w), 0.f);
    float o4 = fmaxf(fmaf(acc4, inv, b1.x), 0.f);
    float o5 = fmaxf(fmaf(acc5, inv, b1.y), 0.f);
    float o6 = fmaxf(fmaf(acc6, inv, b1.z), 0.f);
    float o7 = fmaxf(fmaf(acc7, inv, b1.w), 0.f);
    uint4 pb;
    pb.x = bf16rne(o0) | (bf16rne(o1) << 16);
    pb.y = bf16rne(o2) | (bf16rne(o3) << 16);
    pb.z = bf16rne(o4) | (bf16rne(o5) << 16);
    pb.w = bf16rne(o6) | (bf16rne(o7) << 16);
    *(uint4*)(Ob + (size_t)node * 128 + li * 8) = pb;
  }
}

// ---------------- pooling (batch is sorted; bf16 input) ----------------
__global__ void pool_kernel(const u16* __restrict__ Hb, const int* __restrict__ batch,
                            float* __restrict__ psum, float* __restrict__ pcnt) {
  int t = threadIdx.x;  // 128
  int start = blockIdx.x * PCHUNK;
  int end = min(N_NODES, start + PCHUNK);
  if (start >= end) return;
  int cur = batch[start];
  float acc = 0.f; int cnt = 0;
  for (int i = start; i < end; ++i) {
    int g = batch[i];
    if (g != cur) {
      atomicAdd(&psum[cur * 128 + t], acc);
      if (t == 0) atomicAdd(&pcnt[cur], (float)cnt);
      acc = 0.f; cnt = 0; cur = g;
    }
    acc += bf2f(Hb[(size_t)i * 128 + t]);
    cnt++;
  }
  atomicAdd(&psum[cur * 128 + t], acc);
  if (t == 0) atomicAdd(&pcnt[cur], (float)cnt);
}

// ---------------- FFN head: wide-parallel, short chains ----------------
__global__ __launch_bounds__(128) void ffn1_kernel(const float* __restrict__ psum,
                                                   const float* __restrict__ pcnt,
                                                   const float* __restrict__ Wf1,
                                                   const float* __restrict__ bf1,
                                                   float* __restrict__ z1) {
  __shared__ float prow[128];
  int b = blockIdx.x;
  int g = b >> 2, ch = b & 3;
  int t = threadIdx.x;
  prow[t] = psum[g * 128 + t] / fmaxf(pcnt[g], 1.f);
  __syncthreads();
  int c = ch * 128 + t;
  float a = bf1[c];
#pragma unroll 8
  for (int k = 0; k < 128; ++k) a = fmaf(prow[k], Wf1[k * 512 + c], a);
  z1[g * 512 + c] = fmaxf(a, 0.f);
}

__global__ __launch_bounds__(256) void ffn2_kernel(const float* __restrict__ z1,
                                                   const float* __restrict__ Wf2,
                                                   const float* __restrict__ bf2,
                                                   float* __restrict__ z2) {
  __shared__ float z1s[512];
  __shared__ float part[256];
  int b = blockIdx.x;
  int g = b >> 3, ch = b & 7;
  int t = threadIdx.x;
  z1s[t] = z1[g * 512 + t];
  z1s[t + 256] = z1[g * 512 + t + 256];
  __syncthreads();
  int c = ch * 64 + (t & 63);
  int kq = t >> 6;
  float a = 0.f;
#pragma unroll 8
  for (int kk = 0; kk < 128; ++kk) {
    int k = kq * 128 + kk;
    a = fmaf(z1s[k], Wf2[k * 512 + c], a);
  }
  part[t] = a;
  __syncthreads();
  if (kq == 0) {
    float s = part[t] + part[t + 64] + part[t + 128] + part[t + 192] + bf2[c];
    z2[g * 512 + c] = fmaxf(s, 0.f);
  }
}

__global__ __launch_bounds__(256) void ffn3_kernel(const float* __restrict__ z2,
                                                   const float* __restrict__ Wf3t,
                                                   const float* __restrict__ bf3,
                                                   float* __restrict__ out) {
  int wid = blockIdx.x * 4 + (threadIdx.x >> 6);  // 0..1279
  int lane = threadIdx.x & 63;
  int g = wid / NCLS, c = wid - g * NCLS;
  float a = 0.f;
#pragma unroll
  for (int j = 0; j < 8; ++j) {
    int k = j * 64 + lane;
    a = fmaf(z2[g * 512 + k], Wf3t[c * 512 + k], a);
  }
#pragma unroll
  for (int off = 32; off; off >>= 1) a += __shfl_xor(a, off, 64);
  if (lane == 0) out[g * NCLS + c] = a + bf3[c];
}

extern "C" void kernel_launch(void* const* d_in, const int* in_sizes, int n_in,
                              void* d_out, int out_size, void* d_ws, size_t ws_size,
                              hipStream_t stream) {
  const float* x   = (const float*)d_in[0];
  const int*   ei  = (const int*)d_in[1];
  const int*   bat = (const int*)d_in[2];
  const float* W[3]  = {(const float*)d_in[3], (const float*)d_in[7],  (const float*)d_in[11]};
  const float* As[3] = {(const float*)d_in[4], (const float*)d_in[8],  (const float*)d_in[12]};
  const float* Ad[3] = {(const float*)d_in[5], (const float*)d_in[9],  (const float*)d_in[13]};
  const float* B[3]  = {(const float*)d_in[6], (const float*)d_in[10], (const float*)d_in[14]};
  const float* Wf1 = (const float*)d_in[15]; const float* bf1 = (const float*)d_in[16];
  const float* Wf2 = (const float*)d_in[17]; const float* bf2 = (const float*)d_in[18];
  const float* Wf3 = (const float*)d_in[19]; const float* bf3 = (const float*)d_in[20];
  float* out = (float*)d_out;

  size_t off = 0;
  auto carve = [&](size_t bytes) {
    void* p = (char*)d_ws + off;
    off += (bytes + 255) & ~(size_t)255;
    return p;
  };
  u16*   Ab0    = (u16*)carve((size_t)N_NODES * 128 * 2);
  u16*   Ab1    = (u16*)carve((size_t)N_NODES * 128 * 2);
  u8*    Hf8    = (u8*)carve((size_t)N_NODES * 128);
  u16*   Wt     = (u16*)carve((size_t)3 * 128 * 128 * 2);
  float* as_    = (float*)carve((size_t)N_NODES * 4);
  float* ad_    = (float*)carve((size_t)N_NODES * 4);
  u32*   rldeg  = (u32*)carve((size_t)N_NODES * 4);
  u16*   col    = (u16*)carve((size_t)NB * BCAP * 2);
  u32*   ebuf   = (u32*)carve((size_t)NB * BCAP * 4);
  int*   bcur   = (int*)carve(NB * 4);
  float* psum   = (float*)carve(NG * 128 * 4);
  float* pcnt   = (float*)carve(NG * 4);
  float* z1     = (float*)carve(NG * 512 * 4);
  float* z2     = (float*)carve(NG * 512 * 4);
  float* Wf3t   = (float*)carve((size_t)NCLS * 512 * 4);

  // prep (zero bcur/psum/pcnt, bf16-transpose Wt, fp32-transpose Wf3t)
  prep_kernel<<<256, 256, 0, stream>>>(bcur, psum, pcnt, W[0], W[1], W[2], Wt, Wf3, Wf3t);

  // bucketed CSR build
  int sgrid = (TOT_E + EPW - 1) / EPW;
  scatter_kernel<<<sgrid, 256, 0, stream>>>(ei, bcur, ebuf);
  degfill_kernel<<<NB, 256, 0, stream>>>(bcur, ebuf, rldeg, col);

  // 3 GAT layers (fp8 gather)
  int node_waves_grid = (N_NODES * 64 + 255) / 256;
  gemm_mfma<true><<<3125, 64, 0, stream>>>(x, Wt, As[0], Ad[0], Hf8, as_, ad_);
  agg_kernel<<<node_waves_grid, 256, 0, stream>>>(Hf8, as_, ad_, rldeg, col, B[0], Ab0);
  gemm_mfma<false><<<3125, 64, 0, stream>>>(Ab0, Wt + 16384, As[1], Ad[1], Hf8, as_, ad_);
  agg_kernel<<<node_waves_grid, 256, 0, stream>>>(Hf8, as_, ad_, rldeg, col, B[1], Ab1);
  gemm_mfma<false><<<3125, 64, 0, stream>>>(Ab1, Wt + 32768, As[2], Ad[2], Hf8, as_, ad_);
  agg_kernel<<<node_waves_grid, 256, 0, stream>>>(Hf8, as_, ad_, rldeg, col, B[2], Ab0);

  // mean-pool + FFN head
  pool_kernel<<<(N_NODES + PCHUNK - 1) / PCHUNK, 128, 0, stream>>>(Ab0, bat, psum, pcnt);
  ffn1_kernel<<<NG * 4, 128, 0, stream>>>(psum, pcnt, Wf1, bf1, z1);
  ffn2_kernel<<<NG * 8, 256, 0, stream>>>(z1, Wf2, bf2, z2);
  ffn3_kernel<<<320, 256, 0, stream>>>(z2, Wf3t, bf3, out);
}